// Round 1
// baseline (1855.815 us; speedup 1.0000x reference)
//
#include <hip/hip_runtime.h>
#include <math.h>

#define B_ 4
#define C_ 256
#define HW_ 4096
#define G_ 8
#define CPG_ 32
#define H_ 4
#define DH_ 64
#define GRP_ELEMS (CPG_ * HW_)          // 131072
#define NCHUNK 16
#define CHUNK_ELEMS (GRP_ELEMS / NCHUNK) // 8192
#define EPS 1e-5f

// workspace layout (float offsets)
#define XN_OFF  0
#define XN_SZ   (B_ * C_ * HW_)              // 4,194,304
#define QKV_OFF (XN_OFF + XN_SZ)
#define QKV_SZ  (B_ * 3 * C_ * HW_)          // 12,582,912
#define ATT_OFF (QKV_OFF + QKV_SZ)
#define ATT_SZ  (B_ * C_ * HW_)
#define PART_OFF (ATT_OFF + ATT_SZ)          // 32*16*2 floats

// ---------------- GroupNorm: stage 1, deterministic partial sums ----------
__global__ __launch_bounds__(256) void gn_partial(const float* __restrict__ x,
                                                  float* __restrict__ part) {
    int bg = blockIdx.x >> 4;      // b*8+g  (groups are contiguous in memory)
    int chunk = blockIdx.x & 15;
    const float4* p = (const float4*)(x + (size_t)bg * GRP_ELEMS + (size_t)chunk * CHUNK_ELEMS);
    int t = threadIdx.x;
    float s = 0.f, ss = 0.f;
#pragma unroll
    for (int i = 0; i < 8; ++i) {
        float4 v = p[t + i * 256];
        s  += v.x + v.y + v.z + v.w;
        ss += v.x * v.x + v.y * v.y + v.z * v.z + v.w * v.w;
    }
#pragma unroll
    for (int off = 32; off; off >>= 1) {
        s  += __shfl_xor(s, off, 64);
        ss += __shfl_xor(ss, off, 64);
    }
    __shared__ float ls[8];
    int wave = t >> 6, lane = t & 63;
    if (lane == 0) { ls[wave * 2] = s; ls[wave * 2 + 1] = ss; }
    __syncthreads();
    if (t == 0) {
        float S = 0.f, SS = 0.f;
#pragma unroll
        for (int w = 0; w < 4; ++w) { S += ls[w * 2]; SS += ls[w * 2 + 1]; }
        part[(bg * 16 + chunk) * 2]     = S;
        part[(bg * 16 + chunk) * 2 + 1] = SS;
    }
}

// ---------------- GroupNorm: stage 2, normalize ---------------------------
__global__ __launch_bounds__(256) void gn_norm(const float* __restrict__ x,
                                               const float* __restrict__ gamma,
                                               const float* __restrict__ beta,
                                               const float* __restrict__ part,
                                               float* __restrict__ xn) {
    int bc = blockIdx.x;           // b*256 + ch
    int b = bc >> 8, ch = bc & 255;
    int g = ch >> 5;
    int bg = b * G_ + g;
    float S = 0.f, SS = 0.f;
#pragma unroll
    for (int i = 0; i < 16; ++i) {
        S  += part[(bg * 16 + i) * 2];
        SS += part[(bg * 16 + i) * 2 + 1];
    }
    float mean = S * (1.f / GRP_ELEMS);
    float var  = SS * (1.f / GRP_ELEMS) - mean * mean;
    float inv  = rsqrtf(var + EPS);
    float a  = inv * gamma[ch];
    float bb = beta[ch] - mean * a;
    const float4* xin = (const float4*)(x + (size_t)bc * HW_);
    float4* xo = (float4*)(xn + (size_t)bc * HW_);
    int t = threadIdx.x;
#pragma unroll
    for (int i = 0; i < 4; ++i) {
        float4 v = xin[t + i * 256];
        v.x = v.x * a + bb; v.y = v.y * a + bb;
        v.z = v.z * a + bb; v.w = v.w * a + bb;
        xo[t + i * 256] = v;
    }
}

// ---------------- fp32 tiled GEMM: Out[b] = W(MxK) @ X[b](K x HW) ----------
// grid (HW/64, M/64, B), 256 threads, 64x64 tile, 4x4 micro-tile/thread
template <bool BIAS_RES>
__global__ __launch_bounds__(256) void gemm_wx(const float* __restrict__ W,
                                               const float* __restrict__ X,
                                               float* __restrict__ Out,
                                               const float* __restrict__ bias,
                                               const float* __restrict__ res,
                                               int M) {
    __shared__ float Ws[64][68];   // [k][m]
    __shared__ float Xs[64][68];   // [k][n]
    int b  = blockIdx.z;
    int m0 = blockIdx.y * 64;
    int n0 = blockIdx.x * 64;
    const float* Xb = X + (size_t)b * C_ * HW_;
    float* Ob = Out + (size_t)b * M * HW_;
    int t = threadIdx.x;
    int ti = t >> 4, tj = t & 15;
    float acc[4][4] = {};

    for (int kt = 0; kt < 4; ++kt) {
        {
            int row = t >> 4;          // 0..15
            int q4  = t & 15;
#pragma unroll
            for (int it = 0; it < 4; ++it) {
                int mm = row + 16 * it;
                float4 v = *(const float4*)(W + (size_t)(m0 + mm) * C_ + kt * 64 + q4 * 4);
                Ws[q4 * 4 + 0][mm] = v.x;
                Ws[q4 * 4 + 1][mm] = v.y;
                Ws[q4 * 4 + 2][mm] = v.z;
                Ws[q4 * 4 + 3][mm] = v.w;
                int kk = row + 16 * it;
                float4 xv = *(const float4*)(Xb + (size_t)(kt * 64 + kk) * HW_ + n0 + q4 * 4);
                *(float4*)&Xs[kk][q4 * 4] = xv;
            }
        }
        __syncthreads();
#pragma unroll 8
        for (int kk = 0; kk < 64; ++kk) {
            float4 wv = *(const float4*)&Ws[kk][ti * 4];
            float4 xv = *(const float4*)&Xs[kk][tj * 4];
            float wr[4] = {wv.x, wv.y, wv.z, wv.w};
            float xr[4] = {xv.x, xv.y, xv.z, xv.w};
#pragma unroll
            for (int r = 0; r < 4; ++r)
#pragma unroll
                for (int c = 0; c < 4; ++c)
                    acc[r][c] += wr[r] * xr[c];
        }
        __syncthreads();
    }
#pragma unroll
    for (int r = 0; r < 4; ++r) {
        int m = m0 + ti * 4 + r;
        float bi = BIAS_RES ? bias[m] : 0.f;
        float4 o;
        o.x = acc[r][0] + bi; o.y = acc[r][1] + bi;
        o.z = acc[r][2] + bi; o.w = acc[r][3] + bi;
        if (BIAS_RES) {
            float4 rv = *(const float4*)(res + (size_t)(b * M + m) * HW_ + n0 + tj * 4);
            o.x += rv.x; o.y += rv.y; o.z += rv.z; o.w += rv.w;
        }
        *(float4*)(Ob + (size_t)m * HW_ + n0 + tj * 4) = o;
    }
}

// ---------------- flash attention (fp32 vector), 64-row Q tiles ------------
// grid (HW/64, B*H), 256 threads
__global__ __launch_bounds__(256) void flash_attn(const float* __restrict__ qkv,
                                                  float* __restrict__ att) {
    __shared__ float Qs[64][68];   // [i][d], pre-scaled
    __shared__ float Ks[64][68];   // [j][d]
    __shared__ float Vs[64][68];   // [d][j]
    __shared__ float Ps[64][68];   // [i][j], reused as [d][i] for epilogue
    int bh = blockIdx.y;
    int b = bh >> 2, h = bh & 3;
    int i0 = blockIdx.x * 64;
    const float* qb = qkv + (size_t)b * 3 * C_ * HW_ + (size_t)(h * DH_) * HW_;
    const float* kb = qb + (size_t)C_ * HW_;
    const float* vb = qb + (size_t)2 * C_ * HW_;
    int t = threadIdx.x;
    int ti = t >> 4, tj = t & 15;
    const float scale = rsqrtf((float)(C_ * H_));   // (c*HEADS)^-0.5 = 1/32

    {   // load Q tile transposed -> Qs[i][d], apply scale once
        int drow = t >> 4, i4 = t & 15;
#pragma unroll
        for (int it = 0; it < 4; ++it) {
            int d = drow + 16 * it;
            float4 v = *(const float4*)(qb + (size_t)d * HW_ + i0 + i4 * 4);
            Qs[i4 * 4 + 0][d] = v.x * scale;
            Qs[i4 * 4 + 1][d] = v.y * scale;
            Qs[i4 * 4 + 2][d] = v.z * scale;
            Qs[i4 * 4 + 3][d] = v.w * scale;
        }
    }

    float m[4], l[4], O[4][4];
#pragma unroll
    for (int r = 0; r < 4; ++r) {
        m[r] = -1e30f; l[r] = 0.f;
#pragma unroll
        for (int c = 0; c < 4; ++c) O[r][c] = 0.f;
    }

    for (int j0 = 0; j0 < HW_; j0 += 64) {
        __syncthreads();   // Qs visible (iter 0); Ks/Vs/Ps free from last iter
        {   // K transposed -> Ks[j][d];  V direct -> Vs[d][j]
            int drow = t >> 4, j4 = t & 15;
#pragma unroll
            for (int it = 0; it < 4; ++it) {
                int d = drow + 16 * it;
                float4 kv = *(const float4*)(kb + (size_t)d * HW_ + j0 + j4 * 4);
                Ks[j4 * 4 + 0][d] = kv.x;
                Ks[j4 * 4 + 1][d] = kv.y;
                Ks[j4 * 4 + 2][d] = kv.z;
                Ks[j4 * 4 + 3][d] = kv.w;
                float4 vv = *(const float4*)(vb + (size_t)d * HW_ + j0 + j4 * 4);
                *(float4*)&Vs[d][j4 * 4] = vv;
            }
        }
        __syncthreads();

        // S[r][u]: rows i = 4*ti+r, cols j = tj + 16*u (interleaved)
        float S[4][4];
#pragma unroll
        for (int r = 0; r < 4; ++r)
#pragma unroll
            for (int u = 0; u < 4; ++u) S[r][u] = 0.f;
#pragma unroll 4
        for (int d4 = 0; d4 < 16; ++d4) {
            float4 q[4], k[4];
#pragma unroll
            for (int r = 0; r < 4; ++r) q[r] = *(const float4*)&Qs[ti * 4 + r][d4 * 4];
#pragma unroll
            for (int u = 0; u < 4; ++u) k[u] = *(const float4*)&Ks[tj + 16 * u][d4 * 4];
#pragma unroll
            for (int r = 0; r < 4; ++r)
#pragma unroll
                for (int u = 0; u < 4; ++u)
                    S[r][u] += q[r].x * k[u].x + q[r].y * k[u].y +
                               q[r].z * k[u].z + q[r].w * k[u].w;
        }

        // online softmax (row reduce across 16 lanes)
#pragma unroll
        for (int r = 0; r < 4; ++r) {
            float mx = fmaxf(fmaxf(S[r][0], S[r][1]), fmaxf(S[r][2], S[r][3]));
#pragma unroll
            for (int off = 1; off < 16; off <<= 1) mx = fmaxf(mx, __shfl_xor(mx, off, 64));
            float mn = fmaxf(m[r], mx);
            float alpha = __expf(m[r] - mn);
            m[r] = mn;
            float rs = 0.f;
#pragma unroll
            for (int u = 0; u < 4; ++u) { S[r][u] = __expf(S[r][u] - mn); rs += S[r][u]; }
#pragma unroll
            for (int off = 1; off < 16; off <<= 1) rs += __shfl_xor(rs, off, 64);
            l[r] = l[r] * alpha + rs;
#pragma unroll
            for (int c = 0; c < 4; ++c) O[r][c] *= alpha;
        }

#pragma unroll
        for (int r = 0; r < 4; ++r)
#pragma unroll
            for (int u = 0; u < 4; ++u)
                Ps[ti * 4 + r][tj + 16 * u] = S[r][u];
        __syncthreads();

        // O[r][c] += sum_j P[i][j] * V[d][j],  d = tj + 16*c
#pragma unroll 4
        for (int j4 = 0; j4 < 16; ++j4) {
            float4 p[4], v[4];
#pragma unroll
            for (int r = 0; r < 4; ++r) p[r] = *(const float4*)&Ps[ti * 4 + r][j4 * 4];
#pragma unroll
            for (int c = 0; c < 4; ++c) v[c] = *(const float4*)&Vs[tj + 16 * c][j4 * 4];
#pragma unroll
            for (int r = 0; r < 4; ++r)
#pragma unroll
                for (int c = 0; c < 4; ++c)
                    O[r][c] += p[r].x * v[c].x + p[r].y * v[c].y +
                               p[r].z * v[c].z + p[r].w * v[c].w;
        }
    }

    __syncthreads();
    // normalize, stage transposed as Ps[d][i]
#pragma unroll
    for (int r = 0; r < 4; ++r) {
        float inv = 1.f / l[r];
#pragma unroll
        for (int c = 0; c < 4; ++c)
            Ps[tj + 16 * c][ti * 4 + r] = O[r][c] * inv;
    }
    __syncthreads();
    // coalesced write: att[b][h*64+d][i0+i]
    float* ob = att + (size_t)(b * C_ + h * DH_) * HW_ + i0;
#pragma unroll
    for (int it = 0; it < 4; ++it) {
        int f = t + 256 * it;       // float4 index within 64x64 tile
        int d = f >> 4, i4 = f & 15;
        *(float4*)(ob + (size_t)d * HW_ + i4 * 4) = *(const float4*)&Ps[d][i4 * 4];
    }
}

extern "C" void kernel_launch(void* const* d_in, const int* in_sizes, int n_in,
                              void* d_out, int out_size, void* d_ws, size_t ws_size,
                              hipStream_t stream) {
    const float* x        = (const float*)d_in[0];
    const float* gn_gamma = (const float*)d_in[1];
    const float* gn_beta  = (const float*)d_in[2];
    const float* w_qkv    = (const float*)d_in[3];
    const float* w_proj   = (const float*)d_in[4];
    const float* b_proj   = (const float*)d_in[5];
    float* out = (float*)d_out;
    float* ws  = (float*)d_ws;

    float* xn   = ws + XN_OFF;
    float* qkv  = ws + QKV_OFF;
    float* att  = ws + ATT_OFF;
    float* part = ws + PART_OFF;

    gn_partial<<<dim3(G_ * B_ * NCHUNK), 256, 0, stream>>>(x, part);
    gn_norm<<<dim3(B_ * C_), 256, 0, stream>>>(x, gn_gamma, gn_beta, part, xn);
    gemm_wx<false><<<dim3(HW_ / 64, (3 * C_) / 64, B_), 256, 0, stream>>>(
        w_qkv, xn, qkv, nullptr, nullptr, 3 * C_);
    flash_attn<<<dim3(HW_ / 64, B_ * H_), 256, 0, stream>>>(qkv, att);
    gemm_wx<true><<<dim3(HW_ / 64, C_ / 64, B_), 256, 0, stream>>>(
        w_proj, att, out, b_proj, x, C_);
}

// Round 2
// 587.862 us; speedup vs baseline: 3.1569x; 3.1569x over previous
//
#include <hip/hip_runtime.h>
#include <math.h>

#define B_ 4
#define C_ 256
#define HW_ 4096
#define G_ 8
#define H_ 4
#define DH_ 64
#define GRP_ELEMS (32 * HW_)             // 131072
#define NCHUNK 16
#define CHUNK_ELEMS (GRP_ELEMS / NCHUNK) // 8192
#define EPS 1e-5f

typedef __attribute__((ext_vector_type(8))) short short8;
typedef __attribute__((ext_vector_type(4))) float f32x4;

__device__ __forceinline__ ushort f2bf(float x) {
    unsigned u = __builtin_bit_cast(unsigned, x);
    u += 0x7FFFu + ((u >> 16) & 1u);
    return (ushort)(u >> 16);
}
__device__ __forceinline__ float bf2f(ushort h) {
    unsigned u = ((unsigned)h) << 16;
    return __builtin_bit_cast(float, u);
}

// workspace layout (float-slot offsets)
#define XN_SZ   (B_ * C_ * HW_)          // f32
#define QKV_SZ  (B_ * 3 * C_ * HW_)      // ushort count
#define ATT_SZ  (B_ * C_ * HW_)          // f32
#define QT_SZ   (B_ * C_ * HW_)          // ushort count

// ---------------- GroupNorm stage 1: deterministic partial sums -----------
__global__ __launch_bounds__(256) void gn_partial(const float* __restrict__ x,
                                                  float* __restrict__ part) {
    int bg = blockIdx.x >> 4;
    int chunk = blockIdx.x & 15;
    const float4* p = (const float4*)(x + (size_t)bg * GRP_ELEMS + (size_t)chunk * CHUNK_ELEMS);
    int t = threadIdx.x;
    float s = 0.f, ss = 0.f;
#pragma unroll
    for (int i = 0; i < 8; ++i) {
        float4 v = p[t + i * 256];
        s  += v.x + v.y + v.z + v.w;
        ss += v.x * v.x + v.y * v.y + v.z * v.z + v.w * v.w;
    }
#pragma unroll
    for (int off = 32; off; off >>= 1) {
        s  += __shfl_xor(s, off, 64);
        ss += __shfl_xor(ss, off, 64);
    }
    __shared__ float ls[8];
    int wave = t >> 6, lane = t & 63;
    if (lane == 0) { ls[wave * 2] = s; ls[wave * 2 + 1] = ss; }
    __syncthreads();
    if (t == 0) {
        float S = 0.f, SS = 0.f;
#pragma unroll
        for (int w = 0; w < 4; ++w) { S += ls[w * 2]; SS += ls[w * 2 + 1]; }
        part[(bg * 16 + chunk) * 2]     = S;
        part[(bg * 16 + chunk) * 2 + 1] = SS;
    }
}

// ---------------- GroupNorm stage 2: normalize ----------------------------
__global__ __launch_bounds__(256) void gn_norm(const float* __restrict__ x,
                                               const float* __restrict__ gamma,
                                               const float* __restrict__ beta,
                                               const float* __restrict__ part,
                                               float* __restrict__ xn) {
    int bc = blockIdx.x;
    int b = bc >> 8, ch = bc & 255;
    int g = ch >> 5;
    int bg = b * G_ + g;
    float S = 0.f, SS = 0.f;
#pragma unroll
    for (int i = 0; i < 16; ++i) {
        S  += part[(bg * 16 + i) * 2];
        SS += part[(bg * 16 + i) * 2 + 1];
    }
    float mean = S * (1.f / GRP_ELEMS);
    float var  = SS * (1.f / GRP_ELEMS) - mean * mean;
    float inv  = rsqrtf(var + EPS);
    float a  = inv * gamma[ch];
    float bb = beta[ch] - mean * a;
    const float4* xin = (const float4*)(x + (size_t)bc * HW_);
    float4* xo = (float4*)(xn + (size_t)bc * HW_);
    int t = threadIdx.x;
#pragma unroll
    for (int i = 0; i < 4; ++i) {
        float4 v = xin[t + i * 256];
        v.x = v.x * a + bb; v.y = v.y * a + bb;
        v.z = v.z * a + bb; v.w = v.w * a + bb;
        xo[t + i * 256] = v;
    }
}

// ---------------- fp32 tiled GEMM: Out[b] = W(MxK) @ X[b](K x HW) ----------
template <bool BIAS_RES, bool OUT_BF16>
__global__ __launch_bounds__(256) void gemm_wx(const float* __restrict__ W,
                                               const float* __restrict__ X,
                                               void* __restrict__ Out,
                                               const float* __restrict__ bias,
                                               const float* __restrict__ res,
                                               int M) {
    __shared__ float Ws[64][68];
    __shared__ float Xs[64][68];
    int b  = blockIdx.z;
    int m0 = blockIdx.y * 64;
    int n0 = blockIdx.x * 64;
    const float* Xb = X + (size_t)b * C_ * HW_;
    int t = threadIdx.x;
    int ti = t >> 4, tj = t & 15;
    float acc[4][4] = {};

    for (int kt = 0; kt < 4; ++kt) {
        {
            int row = t >> 4;
            int q4  = t & 15;
#pragma unroll
            for (int it = 0; it < 4; ++it) {
                int mm = row + 16 * it;
                float4 v = *(const float4*)(W + (size_t)(m0 + mm) * C_ + kt * 64 + q4 * 4);
                Ws[q4 * 4 + 0][mm] = v.x;
                Ws[q4 * 4 + 1][mm] = v.y;
                Ws[q4 * 4 + 2][mm] = v.z;
                Ws[q4 * 4 + 3][mm] = v.w;
                int kk = row + 16 * it;
                float4 xv = *(const float4*)(Xb + (size_t)(kt * 64 + kk) * HW_ + n0 + q4 * 4);
                *(float4*)&Xs[kk][q4 * 4] = xv;
            }
        }
        __syncthreads();
#pragma unroll 8
        for (int kk = 0; kk < 64; ++kk) {
            float4 wv = *(const float4*)&Ws[kk][ti * 4];
            float4 xv = *(const float4*)&Xs[kk][tj * 4];
            float wr[4] = {wv.x, wv.y, wv.z, wv.w};
            float xr[4] = {xv.x, xv.y, xv.z, xv.w};
#pragma unroll
            for (int r = 0; r < 4; ++r)
#pragma unroll
                for (int c = 0; c < 4; ++c)
                    acc[r][c] += wr[r] * xr[c];
        }
        __syncthreads();
    }
#pragma unroll
    for (int r = 0; r < 4; ++r) {
        int m = m0 + ti * 4 + r;
        float bi = BIAS_RES ? bias[m] : 0.f;
        float o0 = acc[r][0] + bi, o1 = acc[r][1] + bi;
        float o2 = acc[r][2] + bi, o3 = acc[r][3] + bi;
        if (BIAS_RES) {
            float4 rv = *(const float4*)(res + (size_t)(b * M + m) * HW_ + n0 + tj * 4);
            o0 += rv.x; o1 += rv.y; o2 += rv.z; o3 += rv.w;
        }
        if constexpr (OUT_BF16) {
            ushort* Ob = (ushort*)Out + (size_t)b * M * HW_;
            ushort4 o;
            o.x = f2bf(o0); o.y = f2bf(o1); o.z = f2bf(o2); o.w = f2bf(o3);
            *(ushort4*)(Ob + (size_t)m * HW_ + n0 + tj * 4) = o;
        } else {
            float* Ob = (float*)Out + (size_t)b * M * HW_;
            float4 o; o.x = o0; o.y = o1; o.z = o2; o.w = o3;
            *(float4*)(Ob + (size_t)m * HW_ + n0 + tj * 4) = o;
        }
    }
}

// ---------------- transpose Q,K:  [dh][n] bf16 -> [n][dh] bf16 -------------
// z=0: Q (scaled by (1/32)*log2(e));  z=1: K.   grid (HW/64, B*H, 2)
__global__ __launch_bounds__(256) void transpose_qk(const ushort* __restrict__ qkv,
                                                    ushort* __restrict__ qt,
                                                    ushort* __restrict__ kt) {
    __shared__ __align__(16) ushort Ts[64 * 72];
    int n0 = blockIdx.x * 64;
    int bh = blockIdx.y;
    int b = bh >> 2, h = bh & 3;
    int z = blockIdx.z;
    const ushort* src = qkv + ((size_t)b * 3 * C_ + (size_t)z * C_ + h * DH_) * HW_;
    ushort* dst = (z ? kt : qt) + (size_t)bh * HW_ * DH_;
    const float qscale = 0.045157271f;   // (1/32) * log2(e)
    int t = threadIdx.x;
    int n4 = t & 15, dr = t >> 4;
#pragma unroll
    for (int dt = 0; dt < 4; ++dt) {
        int d = dr + 16 * dt;
        ushort4 v = *(const ushort4*)(src + (size_t)d * HW_ + n0 + n4 * 4);
        if (z == 0) {
            v.x = f2bf(bf2f(v.x) * qscale);
            v.y = f2bf(bf2f(v.y) * qscale);
            v.z = f2bf(bf2f(v.z) * qscale);
            v.w = f2bf(bf2f(v.w) * qscale);
        }
        ushort e[4] = {v.x, v.y, v.z, v.w};
#pragma unroll
        for (int k = 0; k < 4; ++k) {
            int n = n4 * 4 + k;
            Ts[n * 72 + (((d >> 3) ^ ((n >> 2) & 7)) << 3) + (d & 7)] = e[k];
        }
    }
    __syncthreads();
#pragma unroll
    for (int nt = 0; nt < 2; ++nt) {
        int n = (t >> 3) + 32 * nt, d8 = t & 7;
        uint4 val = *(const uint4*)&Ts[n * 72 + ((d8 ^ ((n >> 2) & 7)) << 3)];
        *(uint4*)(dst + (size_t)(n0 + n) * DH_ + d8 * 8) = val;
    }
}

// ---------------- MFMA flash attention (swapped S^T / O^T form) -----------
// grid (HW/64, B*H), 256 thr = 4 indep waves; wave owns 16 i-rows. No barriers.
__global__ __launch_bounds__(256) void flash_attn_mfma(const ushort* __restrict__ qt,
                                                       const ushort* __restrict__ kt,
                                                       const ushort* __restrict__ qkv,
                                                       float* __restrict__ att) {
    __shared__ __align__(16) ushort Pt[64 * 72];   // [i_local][j] bf16
    int bh = blockIdx.y, b = bh >> 2, h = bh & 3;
    int i0 = blockIdx.x * 64;
    int t = threadIdx.x;
    int w = t >> 6, lane = t & 63, l16 = lane & 15, lg = lane >> 4;
    const ushort* qtb = qt + (size_t)bh * HW_ * DH_;
    const ushort* ktb = kt + (size_t)bh * HW_ * DH_;
    const ushort* vb  = qkv + ((size_t)b * 3 * C_ + 2 * C_ + (size_t)h * DH_) * HW_;

    int irow = i0 + 16 * w + l16;            // this lane's i (B-frag col)
    short8 qf[2];
#pragma unroll
    for (int ks = 0; ks < 2; ++ks)
        qf[ks] = *(const short8*)(qtb + (size_t)irow * DH_ + 32 * ks + 8 * lg);

    f32x4 O[4];
#pragma unroll
    for (int dt = 0; dt < 4; ++dt)
#pragma unroll
        for (int r = 0; r < 4; ++r) O[dt][r] = 0.f;
    float m = -1e30f, l = 0.f;

    ushort* Prow = &Pt[(16 * w + l16) * 72];

    for (int j0 = 0; j0 < HW_; j0 += 64) {
        // ---- S^T = K · Q : rows j, cols i -------------------------------
        f32x4 S[4];
#pragma unroll
        for (int jt = 0; jt < 4; ++jt) {
#pragma unroll
            for (int r = 0; r < 4; ++r) S[jt][r] = 0.f;
#pragma unroll
            for (int ks = 0; ks < 2; ++ks) {
                short8 kf = *(const short8*)(ktb + (size_t)(j0 + 16 * jt + l16) * DH_ + 32 * ks + 8 * lg);
                S[jt] = __builtin_amdgcn_mfma_f32_16x16x32_bf16(kf, qf[ks], S[jt], 0, 0, 0);
            }
        }
        // ---- online softmax, lane-local column (log2 domain) ------------
        float mx = S[0][0];
#pragma unroll
        for (int jt = 0; jt < 4; ++jt)
#pragma unroll
            for (int r = 0; r < 4; ++r) mx = fmaxf(mx, S[jt][r]);
        mx = fmaxf(mx, __shfl_xor(mx, 16, 64));
        mx = fmaxf(mx, __shfl_xor(mx, 32, 64));
        float mn = fmaxf(m, mx);
        float alpha = exp2f(m - mn);
        float rs = 0.f;
#pragma unroll
        for (int jt = 0; jt < 4; ++jt)
#pragma unroll
            for (int r = 0; r < 4; ++r) {
                S[jt][r] = exp2f(S[jt][r] - mn);
                rs += S[jt][r];
            }
        rs += __shfl_xor(rs, 16, 64);
        rs += __shfl_xor(rs, 32, 64);
        l = l * alpha + rs;
        m = mn;
#pragma unroll
        for (int dt = 0; dt < 4; ++dt)
#pragma unroll
            for (int r = 0; r < 4; ++r) O[dt][r] *= alpha;

        // ---- P^T -> LDS (packed b64 writes: 4 consecutive j per lane) ---
#pragma unroll
        for (int jt = 0; jt < 4; ++jt) {
            ushort4 pk;
            pk.x = f2bf(S[jt][0]); pk.y = f2bf(S[jt][1]);
            pk.z = f2bf(S[jt][2]); pk.w = f2bf(S[jt][3]);
            *(ushort4*)(Prow + 16 * jt + 4 * lg) = pk;
        }
        // ---- O^T += V^T · P^T -------------------------------------------
        short8 pf[2];
#pragma unroll
        for (int ks = 0; ks < 2; ++ks)
            pf[ks] = *(const short8*)(Prow + 32 * ks + 8 * lg);
#pragma unroll
        for (int dt = 0; dt < 4; ++dt) {
#pragma unroll
            for (int ks = 0; ks < 2; ++ks) {
                short8 vf = *(const short8*)(vb + (size_t)(16 * dt + l16) * HW_ + j0 + 32 * ks + 8 * lg);
                O[dt] = __builtin_amdgcn_mfma_f32_16x16x32_bf16(vf, pf[ks], O[dt], 0, 0, 0);
            }
        }
    }

    // ---- epilogue: O^T layout == att [c][n] layout; direct stores --------
    float inv = 1.f / l;
    float* ab = att + ((size_t)b * C_ + (size_t)h * DH_) * HW_ + i0 + 16 * w + l16;
#pragma unroll
    for (int dt = 0; dt < 4; ++dt)
#pragma unroll
        for (int r = 0; r < 4; ++r)
            ab[(size_t)(16 * dt + 4 * lg + r) * HW_] = O[dt][r] * inv;
}

extern "C" void kernel_launch(void* const* d_in, const int* in_sizes, int n_in,
                              void* d_out, int out_size, void* d_ws, size_t ws_size,
                              hipStream_t stream) {
    const float* x        = (const float*)d_in[0];
    const float* gn_gamma = (const float*)d_in[1];
    const float* gn_beta  = (const float*)d_in[2];
    const float* w_qkv    = (const float*)d_in[3];
    const float* w_proj   = (const float*)d_in[4];
    const float* b_proj   = (const float*)d_in[5];
    float* out = (float*)d_out;
    float* ws  = (float*)d_ws;

    float*  xn   = ws;
    ushort* qkv  = (ushort*)(ws + XN_SZ);
    float*  att  = ws + XN_SZ + QKV_SZ / 2;
    ushort* qt   = (ushort*)(att + ATT_SZ);
    ushort* kt   = qt + QT_SZ;
    float*  part = (float*)(kt + QT_SZ);

    gn_partial<<<dim3(G_ * B_ * NCHUNK), 256, 0, stream>>>(x, part);
    gn_norm<<<dim3(B_ * C_), 256, 0, stream>>>(x, gn_gamma, gn_beta, part, xn);
    gemm_wx<false, true><<<dim3(HW_ / 64, (3 * C_) / 64, B_), 256, 0, stream>>>(
        w_qkv, xn, (void*)qkv, nullptr, nullptr, 3 * C_);
    transpose_qk<<<dim3(HW_ / 64, B_ * H_, 2), 256, 0, stream>>>(qkv, qt, kt);
    flash_attn_mfma<<<dim3(HW_ / 64, B_ * H_), 256, 0, stream>>>(qt, kt, qkv, att);
    gemm_wx<true, false><<<dim3(HW_ / 64, C_ / 64, B_), 256, 0, stream>>>(
        w_proj, att, (void*)out, b_proj, x, C_);
}